// Round 2
// baseline (1442.651 us; speedup 1.0000x reference)
//
#include <hip/hip_runtime.h>

// VecInt scaling-and-squaring, SoA intermediate layout.
// disp = vel / 2^7; repeat 7x: disp = disp + trilinear_sample(disp, grid + disp).
// Round-1 was L1 line-transaction bound (AoS 12B/voxel => ~12 lines per gather
// load per wave). SoA channels cut line-touches 3x -> HBM-bound (~40us/step).
// Buffers: ws (118MB) and d_out (118MB) ping-pong in SoA; final step emits AoS.

namespace {

constexpr int Dd = 160, Hh = 192, Ww = 160, Bb = 2;
constexpr int HW  = Hh * Ww;                 // 30720
constexpr int VOX = Dd * Hh * Ww;            // 4,915,200 per batch
constexpr int NTOT = Bb * VOX;               // 9,830,400 voxels
constexpr int C = NTOT;                      // SoA channel stride (floats)

// ---- scale + AoS->SoA transpose: out_c[v] = in[v*3+c] / 128 ----
__global__ __launch_bounds__(256) void scale_t_k(const float* __restrict__ in,
                                                 float* __restrict__ out) {
    __shared__ float tile[768];
    int t = threadIdx.x;
    int v0 = blockIdx.x * 256;
    const float* src = in + (long long)v0 * 3;
    tile[t]       = src[t];
    tile[t + 256] = src[t + 256];
    tile[t + 512] = src[t + 512];
    __syncthreads();
    constexpr float s = 1.0f / 128.0f;
    out[0 * C + v0 + t] = tile[3 * t + 0] * s;
    out[1 * C + v0 + t] = tile[3 * t + 1] * s;
    out[2 * C + v0 + t] = tile[3 * t + 2] * s;
}

// ---- one squaring step, SoA in / SoA out ----
__device__ __forceinline__ void step_core(const float* __restrict__ A, int idx,
                                          float& r0, float& r1, float& r2) {
    int b = (idx >= VOX) ? 1 : 0;
    int v = idx - b * VOX;
    int z = v / HW;
    int rem = v - z * HW;
    int y = rem / Ww;
    int x = rem - y * Ww;

    float d0 = A[idx];           // z-displacement (ij: channel 0 = D axis)
    float d1 = A[C + idx];       // y
    float d2 = A[2 * C + idx];   // x

    float lz = fminf(fmaxf((float)z + d0, 0.0f), (float)(Dd - 1));
    float ly = fminf(fmaxf((float)y + d1, 0.0f), (float)(Hh - 1));
    float lx = fminf(fmaxf((float)x + d2, 0.0f), (float)(Ww - 1));

    float fz = floorf(lz), fy = floorf(ly), fx = floorf(lx);
    int z0 = (int)fz, y0 = (int)fy, x0 = (int)fx;
    int z1 = min(z0 + 1, Dd - 1);
    int y1 = min(y0 + 1, Hh - 1);
    int x1 = min(x0 + 1, Ww - 1);
    float tz = lz - fz, ty = ly - fy, tx = lx - fx;
    float sz = 1.0f - tz, sy = 1.0f - ty, sx = 1.0f - tx;

    float w000 = sz * sy * sx, w001 = sz * sy * tx;
    float w010 = sz * ty * sx, w011 = sz * ty * tx;
    float w100 = tz * sy * sx, w101 = tz * sy * tx;
    float w110 = tz * ty * sx, w111 = tz * ty * tx;

    int base = b * VOX;
    int o00 = base + (z0 * Hh + y0) * Ww;
    int o01 = base + (z0 * Hh + y1) * Ww;
    int o10 = base + (z1 * Hh + y0) * Ww;
    int o11 = base + (z1 * Hh + y1) * Ww;

    int p0 = o00 + x0, p1 = o00 + x1;
    int p2 = o01 + x0, p3 = o01 + x1;
    int p4 = o10 + x0, p5 = o10 + x1;
    int p6 = o11 + x0, p7 = o11 + x1;

    float a0 = w000 * A[p0] + w001 * A[p1] + w010 * A[p2] + w011 * A[p3]
             + w100 * A[p4] + w101 * A[p5] + w110 * A[p6] + w111 * A[p7];
    const float* Ay = A + C;
    float a1 = w000 * Ay[p0] + w001 * Ay[p1] + w010 * Ay[p2] + w011 * Ay[p3]
             + w100 * Ay[p4] + w101 * Ay[p5] + w110 * Ay[p6] + w111 * Ay[p7];
    const float* Ax = A + 2 * C;
    float a2 = w000 * Ax[p0] + w001 * Ax[p1] + w010 * Ax[p2] + w011 * Ax[p3]
             + w100 * Ax[p4] + w101 * Ax[p5] + w110 * Ax[p6] + w111 * Ax[p7];

    r0 = d0 + a0;
    r1 = d1 + a1;
    r2 = d2 + a2;
}

__global__ __launch_bounds__(256) void step_soa_k(const float* __restrict__ A,
                                                  float* __restrict__ B) {
    int idx = blockIdx.x * blockDim.x + threadIdx.x;
    float r0, r1, r2;
    step_core(A, idx, r0, r1, r2);
    B[idx]         = r0;
    B[C + idx]     = r1;
    B[2 * C + idx] = r2;
}

// ---- final step: SoA in, AoS out (LDS repack for coalesced stores) ----
__global__ __launch_bounds__(256) void step_final_k(const float* __restrict__ A,
                                                    float* __restrict__ out) {
    int t = threadIdx.x;
    int idx = blockIdx.x * 256 + t;
    float r0, r1, r2;
    step_core(A, idx, r0, r1, r2);
    __shared__ float tile[768];
    tile[3 * t + 0] = r0;
    tile[3 * t + 1] = r1;
    tile[3 * t + 2] = r2;
    __syncthreads();
    float* dst = out + (long long)blockIdx.x * 768;
    dst[t]       = tile[t];
    dst[t + 256] = tile[t + 256];
    dst[t + 512] = tile[t + 512];
}

}  // namespace

extern "C" void kernel_launch(void* const* d_in, const int* in_sizes, int n_in,
                              void* d_out, int out_size, void* d_ws, size_t ws_size,
                              hipStream_t stream) {
    const float* vel = (const float*)d_in[0];
    float* out = (float*)d_out;
    float* W   = (float*)d_ws;   // SoA buffer A (118 MB)
    float* O   = (float*)d_out;  // SoA buffer B = d_out reused as scratch

    constexpr int blk = 256;
    constexpr int grd = NTOT / blk;  // 38400, exact

    // disp0 = vel / 128, AoS->SoA, into W
    scale_t_k<<<grd, blk, 0, stream>>>(vel, W);

    // steps 1..6 ping-pong W <-> O (ends in W)
    float* a = W;
    float* b = O;
    for (int it = 0; it < 6; ++it) {
        step_soa_k<<<grd, blk, 0, stream>>>(a, b);
        float* tmp = a; a = b; b = tmp;
    }
    // step 7: SoA -> AoS into d_out
    step_final_k<<<grd, blk, 0, stream>>>(a, out);
}